// Round 6
// baseline (740.372 us; speedup 1.0000x reference)
//
#include <hip/hip_runtime.h>
#include <math.h>

#define N_NODES 40000
#define N_EDGES 640000
#define HID 128
#define MAXW 64      // in-degree ~ Poisson(16); P(deg > 64) ~ 1e-19 -> never drops edges
#define ITERS 8      // full iterations after initial state = tanh(xproj)
#define NH (N_NODES * HID)
#define NBLK (N_NODES / 32)   // fused-kernel blocks (32 nodes each)

typedef __bf16 bf16x8 __attribute__((ext_vector_type(8)));
typedef __bf16 bf16x4 __attribute__((ext_vector_type(4)));
typedef float floatx4 __attribute__((ext_vector_type(4)));

// Fill ELL with pad index N_NODES, zero deg + per-block max, zero pad rows.
__global__ __launch_bounds__(256) void init_kernel(int* __restrict__ ell,
                                                   int* __restrict__ deg,
                                                   int* __restrict__ bmax,
                                                   __bf16* __restrict__ padA,
                                                   __bf16* __restrict__ padB) {
    int i = blockIdx.x * 256 + threadIdx.x;   // N_EDGES threads
    int4 pad = {N_NODES, N_NODES, N_NODES, N_NODES};
    ((int4*)ell)[i] = pad;                    // N*MAXW/4 = 640000 int4 exactly
    if (i < N_NODES) deg[i] = 0;
    if (i < NBLK) bmax[i] = 0;
    if (i < HID / 8) {
        bf16x8 z;
#pragma unroll
        for (int j = 0; j < 8; ++j) z[j] = (__bf16)0.f;
        ((bf16x8*)padA)[i] = z;
        ((bf16x8*)padB)[i] = z;
    }
}

__global__ __launch_bounds__(256) void build_ell_kernel(const int* __restrict__ ei,
                                                        int* __restrict__ deg,
                                                        int* __restrict__ bmax,
                                                        int* __restrict__ ell) {
    int e = blockIdx.x * 256 + threadIdx.x;
    if (e >= N_EDGES) return;
    int s = ei[e];            // src
    int d = ei[N_EDGES + e];  // dst
    int c = atomicAdd(&deg[d], 1);
    if (c < MAXW) {
        ell[d * MAXW + c] = s;
        atomicMax(&bmax[d >> 5], c + 1);   // block max in-degree (capped at 64)
    }
}

// Pack W (or W^T) into B-fragment order for mfma_f32_16x16x32_bf16:
// pk[((c*8+t)*64 + lane)*8 + j] = B[k = c*32 + (lane>>4)*8 + j][n = t*16 + (lane&15)]
__global__ __launch_bounds__(256) void pack_w_kernel(const float* __restrict__ w,
                                                     __bf16* __restrict__ pk, int trans) {
    int f = blockIdx.x * 256 + threadIdx.x;  // 16384 total
    int j = f & 7, l = (f >> 3) & 63, t = (f >> 9) & 7, c = f >> 12;
    int k = c * 32 + (l >> 4) * 8 + j;
    int n = t * 16 + (l & 15);
    float v = trans ? w[n * HID + k] : w[k * HID + n];
    pk[f] = (__bf16)v;
}

__global__ __launch_bounds__(256) void cast_bf16_kernel(const float* __restrict__ x,
                                                        __bf16* __restrict__ o) {
    int i = blockIdx.x * 256 + threadIdx.x;   // NH/4 threads
    float4 v = ((const float4*)x)[i];
    bf16x4 b;
    b[0] = (__bf16)v.x; b[1] = (__bf16)v.y; b[2] = (__bf16)v.z; b[3] = (__bf16)v.w;
    ((bf16x4*)o)[i] = b;
}

// xproj GEMM (runs twice): xp_bf = A @ B (bf16, pre-tanh), st_bf = tanh(...).
// tanh is computed from the f32 accumulator (full precision); only the stored
// xproj is bf16 (|xproj| ~ 0.5 -> quant err ~1e-3, negligible).
__global__ __launch_bounds__(256) void mfma_gemm_kernel(const __bf16* A,
                                                        const __bf16* __restrict__ Bpk,
                                                        __bf16* __restrict__ xp_bf,
                                                        __bf16* st_bf) {
    __shared__ float tile[4][16][132];
    int tid = threadIdx.x;
    int wv = tid >> 6, lane = tid & 63;
    int q = lane >> 4, cl = lane & 15;

    int row_a = blockIdx.x * 64 + wv * 16 + cl;
    bf16x8 a[4];
#pragma unroll
    for (int c = 0; c < 4; ++c)
        a[c] = *(const bf16x8*)(A + (size_t)row_a * HID + c * 32 + q * 8);

#pragma unroll
    for (int t = 0; t < 8; ++t) {
        floatx4 acc_t = {0.f, 0.f, 0.f, 0.f};
#pragma unroll
        for (int c = 0; c < 4; ++c) {
            bf16x8 b = *(const bf16x8*)(Bpk + (((c * 8 + t) * 64 + lane) << 3));
            acc_t = __builtin_amdgcn_mfma_f32_16x16x32_bf16(a[c], b, acc_t, 0, 0, 0);
        }
#pragma unroll
        for (int r = 0; r < 4; ++r)
            tile[wv][q * 4 + r][t * 16 + cl] = acc_t[r];
    }
    int row = lane >> 2, seg = lane & 3;
    size_t goff = (size_t)(blockIdx.x * 64 + wv * 16 + row) * HID + seg * 32;
    float v[32];
#pragma unroll
    for (int j = 0; j < 8; ++j) {
        floatx4 t4 = *(floatx4*)&tile[wv][row][seg * 32 + j * 4];
        v[j * 4] = t4[0]; v[j * 4 + 1] = t4[1]; v[j * 4 + 2] = t4[2]; v[j * 4 + 3] = t4[3];
    }
#pragma unroll
    for (int j = 0; j < 4; ++j) {
        bf16x8 o;
#pragma unroll
        for (int k = 0; k < 8; ++k) o[k] = (__bf16)v[j * 8 + k];
        *(bf16x8*)(xp_bf + goff + j * 8) = o;   // pre-tanh, bf16
    }
#pragma unroll
    for (int i = 0; i < 32; ++i) v[i] = tanhf(v[i]);
#pragma unroll
    for (int j = 0; j < 4; ++j) {
        bf16x8 o;
#pragma unroll
        for (int k = 0; k < 8; ++k) o[k] = (__bf16)v[j * 8 + k];
        *(bf16x8*)(st_bf + goff + j * 8) = o;
    }
}

// Fused iteration v3: state_out = tanh(xproj + gather(state_in) @ W).
// vs round 5: (a) ELL staged only to the block's max degree (bmax) -> ~2x less
// ELL traffic (was 75% padding); (b) gather unrolled x2 over groups -> 16
// outstanding 16B loads/wave (was 8); (c) xproj read as bf16 (-10MB/iter).
// Pad slots hit the zero row; group counts rounded to even so the x2 unroll
// never reads unstaged LDS.
__global__ __launch_bounds__(256) void fused_iter_kernel(
    const __bf16* __restrict__ state_in,
    __bf16* __restrict__ state_out,
    const int* __restrict__ ell,
    const int* __restrict__ deg,
    const int* __restrict__ bmax,
    const __bf16* __restrict__ Bpk,
    const __bf16* __restrict__ xproj,
    float* __restrict__ st_f32) {
    __shared__ __align__(16) char smem[17408];
    int(*ell_lds)[68] = (int(*)[68])smem;                    // [32][68] int: 8704 B
    __bf16(*aggr_lds)[136] = (__bf16(*)[136])(smem + 8704);  // [32][136] bf16: 8704 B
    float(*tile)[16][68] = (float(*)[16][68])smem;           // [4][16][68] f32: 17408 B

    int tid = threadIdx.x;
    int wv = tid >> 6, lane = tid & 63;
    int q = lane >> 4, f = lane & 15;
    int nb = blockIdx.x * 32;

    // stage ELL columns 0 .. gcnt*4 (gcnt even, >= any node's group count)
    int gcnt = ((bmax[blockIdx.x] + 7) >> 3) << 1;
    for (int g = tid >> 5; g < gcnt; g += 8) {
        int n = tid & 31;
        *(int4*)&ell_lds[n][g * 4] = *(const int4*)&ell[(nb + n) * MAXW + g * 4];
    }
    int degv = deg[nb + (lane & 31)];
    __syncthreads();

    // ---- phase 1: quarter q of wave wv aggregates nodes wv*8+q and wv*8+4+q ----
    int n0 = wv * 8 + q;
    int n1 = wv * 8 + 4 + q;
    int c0 = __shfl(degv, n0), c1 = __shfl(degv, n1);
    int cm = c0 > c1 ? c0 : c1;
    if (cm > MAXW) cm = MAXW;
    int gmax = ((cm + 7) >> 3) << 1;       // even group count <= gcnt
    float acc0[8], acc1[8];
#pragma unroll
    for (int j = 0; j < 8; ++j) { acc0[j] = 0.f; acc1[j] = 0.f; }
    for (int g = 0; g < gmax; g += 2) {
        int b0 = g * 4;
        int sA[8], sB[8];
#pragma unroll
        for (int u = 0; u < 8; ++u) { sA[u] = ell_lds[n0][b0 + u]; sB[u] = ell_lds[n1][b0 + u]; }
        bf16x8 vA[8], vB[8];
#pragma unroll
        for (int u = 0; u < 8; ++u)
            vA[u] = *(const bf16x8*)(state_in + (size_t)sA[u] * HID + f * 8);
#pragma unroll
        for (int u = 0; u < 8; ++u)
            vB[u] = *(const bf16x8*)(state_in + (size_t)sB[u] * HID + f * 8);
#pragma unroll
        for (int j = 0; j < 8; ++j) {
            float a0 = 0.f, a1 = 0.f;
#pragma unroll
            for (int u = 0; u < 8; ++u) { a0 += (float)vA[u][j]; a1 += (float)vB[u][j]; }
            acc0[j] += a0;
            acc1[j] += a1;
        }
    }
    {
        bf16x8 o0, o1;
#pragma unroll
        for (int j = 0; j < 8; ++j) { o0[j] = (__bf16)acc0[j]; o1[j] = (__bf16)acc1[j]; }
        *(bf16x8*)&aggr_lds[n0][f * 8] = o0;
        *(bf16x8*)&aggr_lds[n1][f * 8] = o1;
    }
    __syncthreads();

    // ---- phase 2: waves {0,1}->rows 0-15, {2,3}->rows 16-31; h=wv&1 -> col half ----
    int rg = wv >> 1, h = wv & 1;
    bf16x8 a[4];
#pragma unroll
    for (int c = 0; c < 4; ++c)
        a[c] = *(const bf16x8*)&aggr_lds[rg * 16 + f][c * 32 + q * 8];
    __syncthreads();   // overlay safety: all aggr/ell reads done before tile writes

#pragma unroll
    for (int t = 0; t < 4; ++t) {
        floatx4 acc_t = {0.f, 0.f, 0.f, 0.f};
#pragma unroll
        for (int c = 0; c < 4; ++c) {
            bf16x8 b = *(const bf16x8*)(Bpk + (((c * 8 + h * 4 + t) * 64 + lane) << 3));
            acc_t = __builtin_amdgcn_mfma_f32_16x16x32_bf16(a[c], b, acc_t, 0, 0, 0);
        }
#pragma unroll
        for (int r = 0; r < 4; ++r)
            tile[wv][q * 4 + r][t * 16 + f] = acc_t[r];
    }

    // epilogue: wave covers rows rg*16..+15, global cols h*64..+63 (16 floats/lane)
    int row = lane >> 2, seg = lane & 3;
    size_t goff = (size_t)(nb + rg * 16 + row) * HID + h * 64 + seg * 16;
    float v[16];
    bf16x8 bx0 = *(const bf16x8*)(xproj + goff);
    bf16x8 bx1 = *(const bf16x8*)(xproj + goff + 8);
#pragma unroll
    for (int j = 0; j < 4; ++j) {
        floatx4 t4 = *(floatx4*)&tile[wv][row][seg * 16 + j * 4];
        v[j * 4] = t4[0]; v[j * 4 + 1] = t4[1]; v[j * 4 + 2] = t4[2]; v[j * 4 + 3] = t4[3];
    }
#pragma unroll
    for (int k = 0; k < 8; ++k) { v[k] += (float)bx0[k]; v[8 + k] += (float)bx1[k]; }
#pragma unroll
    for (int i = 0; i < 16; ++i) v[i] = tanhf(v[i]);
#pragma unroll
    for (int j = 0; j < 2; ++j) {
        bf16x8 o;
#pragma unroll
        for (int k = 0; k < 8; ++k) o[k] = (__bf16)v[j * 8 + k];
        *(bf16x8*)(state_out + goff + j * 8) = o;
    }
    if (st_f32) {
#pragma unroll
        for (int j = 0; j < 4; ++j) {
            float4 o = {v[j * 4], v[j * 4 + 1], v[j * 4 + 2], v[j * 4 + 3]};
            *(float4*)(st_f32 + goff + j * 4) = o;
        }
    }
}

extern "C" void kernel_launch(void* const* d_in, const int* in_sizes, int n_in,
                              void* d_out, int out_size, void* d_ws, size_t ws_size,
                              hipStream_t stream) {
    const int* ei = (const int*)d_in[0];       // edge_index [2][E]
    const float* x = (const float*)d_in[1];    // [N][128] f32
    const float* w_in0 = (const float*)d_in[2];
    const float* w_rec0 = (const float*)d_in[3];
    const float* w_in1 = (const float*)d_in[4];
    const float* w_rec1 = (const float*)d_in[5];
    float* out = (float*)d_out;

    // workspace carve (~42 MB total)
    __bf16* xproj_bf = (__bf16*)d_ws;              // NH bf16 (10.24 MB)
    __bf16* stateA = xproj_bf + NH;                // NH + HID bf16 (pad row)
    __bf16* stateB = stateA + NH + HID;            // NH + HID bf16 (pad row); x_bf first
    __bf16* packs = stateB + NH + HID;             // 4 x 16384 bf16
    int* deg = (int*)(packs + 4 * 16384);          // N
    int* bmax = deg + N_NODES;                     // NBLK
    int* ell = bmax + NBLK;                        // N*MAXW (10.24 MB)
    __bf16* pk_in0 = packs;
    __bf16* pk_rec0 = packs + 16384;
    __bf16* pk_in1 = packs + 2 * 16384;
    __bf16* pk_rec1 = packs + 3 * 16384;

    init_kernel<<<N_EDGES / 256, 256, 0, stream>>>(ell, deg, bmax, stateA + NH,
                                                   stateB + NH);
    build_ell_kernel<<<N_EDGES / 256, 256, 0, stream>>>(ei, deg, bmax, ell);
    pack_w_kernel<<<64, 256, 0, stream>>>(w_in0, pk_in0, 1);   // B = w_in0^T
    pack_w_kernel<<<64, 256, 0, stream>>>(w_rec0, pk_rec0, 0); // B = w_rec0
    pack_w_kernel<<<64, 256, 0, stream>>>(w_in1, pk_in1, 1);
    pack_w_kernel<<<64, 256, 0, stream>>>(w_rec1, pk_rec1, 0);
    cast_bf16_kernel<<<NH / 4 / 256, 256, 0, stream>>>(x, stateB);  // x_bf in stateB

    for (int layer = 0; layer < 2; ++layer) {
        const __bf16* pk_in = layer ? pk_in1 : pk_in0;
        const __bf16* pk_rec = layer ? pk_rec1 : pk_rec0;
        // xproj = (layer ? h0 : x_bf) @ w_in^T ; stateA = tanh(xproj).
        // layer 1: A aliases st_bf (each wave reads its own rows first — safe).
        const __bf16* xin = layer ? stateA : stateB;
        mfma_gemm_kernel<<<625, 256, 0, stream>>>(xin, pk_in, xproj_bf, stateA);
        // 8 ping-pong iterations: A->B, B->A, ... ends in stateA.
        for (int it = 0; it < ITERS; ++it) {
            const __bf16* sin = (it & 1) ? stateB : stateA;
            __bf16* sout = (it & 1) ? stateA : stateB;
            float* f32out = (layer == 1 && it == ITERS - 1) ? out : nullptr;
            fused_iter_kernel<<<NBLK, 256, 0, stream>>>(sin, sout, ell, deg, bmax,
                                                        pk_rec, xproj_bf, f32out);
        }
    }
}

// Round 7
// 716.248 us; speedup vs baseline: 1.0337x; 1.0337x over previous
//
#include <hip/hip_runtime.h>
#include <math.h>

#define N_NODES 40000
#define N_EDGES 640000
#define HID 128
#define MAXW 64      // in-degree ~ Poisson(16); P(deg > 64) ~ 1e-19 -> never drops edges
#define ITERS 8      // full iterations after initial state = tanh(xproj)
#define NH (N_NODES * HID)
#define NPB 16                  // nodes per fused block
#define FBLK (N_NODES / NPB)    // 2500 fused blocks

typedef __bf16 bf16x8 __attribute__((ext_vector_type(8)));
typedef __bf16 bf16x4 __attribute__((ext_vector_type(4)));
typedef float floatx4 __attribute__((ext_vector_type(4)));

// Fill ELL with pad index N_NODES, zero deg + degree histogram, zero pad rows.
__global__ __launch_bounds__(256) void init_kernel(int* __restrict__ ell,
                                                   int* __restrict__ deg,
                                                   int* __restrict__ hist,
                                                   __bf16* __restrict__ padA,
                                                   __bf16* __restrict__ padB) {
    int i = blockIdx.x * 256 + threadIdx.x;   // N_EDGES threads
    int4 pad = {N_NODES, N_NODES, N_NODES, N_NODES};
    ((int4*)ell)[i] = pad;                    // N*MAXW/4 = 640000 int4 exactly
    if (i < N_NODES) deg[i] = 0;
    if (i < 65) hist[i] = 0;
    if (i < HID / 8) {
        bf16x8 z;
#pragma unroll
        for (int j = 0; j < 8; ++j) z[j] = (__bf16)0.f;
        ((bf16x8*)padA)[i] = z;
        ((bf16x8*)padB)[i] = z;
    }
}

// No per-block atomicMax here (round 6: 640K atomics on 1250 addrs = 142us).
__global__ __launch_bounds__(256) void build_ell_kernel(const int* __restrict__ ei,
                                                        int* __restrict__ deg,
                                                        int* __restrict__ ell) {
    int e = blockIdx.x * 256 + threadIdx.x;
    if (e >= N_EDGES) return;
    int s = ei[e];            // src
    int d = ei[N_EDGES + e];  // dst
    int c = atomicAdd(&deg[d], 1);
    if (c < MAXW) ell[d * MAXW + c] = s;
}

// Counting sort by degree (descending): hist -> bases -> perm.
__global__ __launch_bounds__(256) void hist_kernel(const int* __restrict__ deg,
                                                   int* __restrict__ hist) {
    int i = blockIdx.x * 256 + threadIdx.x;
    if (i >= N_NODES) return;
    int d = deg[i]; if (d > MAXW) d = MAXW;
    atomicAdd(&hist[d], 1);
}

__global__ void scan_kernel(const int* __restrict__ hist, int* __restrict__ cursor) {
    if (threadIdx.x == 0) {        // 65 bins, serial: trivial
        int run = 0;
        for (int d = MAXW; d >= 0; --d) { cursor[d] = run; run += hist[d]; }
    }
}

__global__ __launch_bounds__(256) void build_perm_kernel(const int* __restrict__ deg,
                                                         int* __restrict__ cursor,
                                                         int* __restrict__ perm) {
    int i = blockIdx.x * 256 + threadIdx.x;
    if (i >= N_NODES) return;
    int d = deg[i]; if (d > MAXW) d = MAXW;
    int slot = atomicAdd(&cursor[d], 1);
    perm[slot] = i;                // descending degree: heavy blocks dispatch first
}

// Pack W (or W^T) into B-fragment order for mfma_f32_16x16x32_bf16:
// pk[((c*8+t)*64 + lane)*8 + j] = B[k = c*32 + (lane>>4)*8 + j][n = t*16 + (lane&15)]
__global__ __launch_bounds__(256) void pack_w_kernel(const float* __restrict__ w,
                                                     __bf16* __restrict__ pk, int trans) {
    int f = blockIdx.x * 256 + threadIdx.x;  // 16384 total
    int j = f & 7, l = (f >> 3) & 63, t = (f >> 9) & 7, c = f >> 12;
    int k = c * 32 + (l >> 4) * 8 + j;
    int n = t * 16 + (l & 15);
    float v = trans ? w[n * HID + k] : w[k * HID + n];
    pk[f] = (__bf16)v;
}

__global__ __launch_bounds__(256) void cast_bf16_kernel(const float* __restrict__ x,
                                                        __bf16* __restrict__ o) {
    int i = blockIdx.x * 256 + threadIdx.x;   // NH/4 threads
    float4 v = ((const float4*)x)[i];
    bf16x4 b;
    b[0] = (__bf16)v.x; b[1] = (__bf16)v.y; b[2] = (__bf16)v.z; b[3] = (__bf16)v.w;
    ((bf16x4*)o)[i] = b;
}

// xproj GEMM (runs twice): xp_bf = A @ B (bf16 pre-tanh), st_bf = tanh(...).
__global__ __launch_bounds__(256) void mfma_gemm_kernel(const __bf16* A,
                                                        const __bf16* __restrict__ Bpk,
                                                        __bf16* __restrict__ xp_bf,
                                                        __bf16* st_bf) {
    __shared__ float tile[4][16][132];
    int tid = threadIdx.x;
    int wv = tid >> 6, lane = tid & 63;
    int q = lane >> 4, cl = lane & 15;

    int row_a = blockIdx.x * 64 + wv * 16 + cl;
    bf16x8 a[4];
#pragma unroll
    for (int c = 0; c < 4; ++c)
        a[c] = *(const bf16x8*)(A + (size_t)row_a * HID + c * 32 + q * 8);

#pragma unroll
    for (int t = 0; t < 8; ++t) {
        floatx4 acc_t = {0.f, 0.f, 0.f, 0.f};
#pragma unroll
        for (int c = 0; c < 4; ++c) {
            bf16x8 b = *(const bf16x8*)(Bpk + (((c * 8 + t) * 64 + lane) << 3));
            acc_t = __builtin_amdgcn_mfma_f32_16x16x32_bf16(a[c], b, acc_t, 0, 0, 0);
        }
#pragma unroll
        for (int r = 0; r < 4; ++r)
            tile[wv][q * 4 + r][t * 16 + cl] = acc_t[r];
    }
    int row = lane >> 2, seg = lane & 3;
    size_t goff = (size_t)(blockIdx.x * 64 + wv * 16 + row) * HID + seg * 32;
    float v[32];
#pragma unroll
    for (int j = 0; j < 8; ++j) {
        floatx4 t4 = *(floatx4*)&tile[wv][row][seg * 32 + j * 4];
        v[j * 4] = t4[0]; v[j * 4 + 1] = t4[1]; v[j * 4 + 2] = t4[2]; v[j * 4 + 3] = t4[3];
    }
#pragma unroll
    for (int j = 0; j < 4; ++j) {
        bf16x8 o;
#pragma unroll
        for (int k = 0; k < 8; ++k) o[k] = (__bf16)v[j * 8 + k];
        *(bf16x8*)(xp_bf + goff + j * 8) = o;   // pre-tanh, bf16
    }
#pragma unroll
    for (int i = 0; i < 32; ++i) v[i] = tanhf(v[i]);
#pragma unroll
    for (int j = 0; j < 4; ++j) {
        bf16x8 o;
#pragma unroll
        for (int k = 0; k < 8; ++k) o[k] = (__bf16)v[j * 8 + k];
        *(bf16x8*)(st_bf + goff + j * 8) = o;
    }
}

// Fused iteration v4: state_out = tanh(xproj + gather(state_in) @ W).
// 16 nodes/block (degree-sorted via perm -> uniform trip counts), 2500 blocks.
// VGPR capped at 64 (__launch_bounds__(256,8)) + 8.8 KB LDS -> 8 blocks/CU =
// 32 waves/CU (round 5/6 ran ~16-19). One node per 16-lane quarter, exact
// per-node trip count, 8 outstanding 16B loads. Pad slots hit the zero row.
__global__ __launch_bounds__(256, 8) void fused_iter_kernel(
    const __bf16* __restrict__ state_in,
    __bf16* __restrict__ state_out,
    const int* __restrict__ ell,
    const int* __restrict__ deg,
    const int* __restrict__ perm,
    const __bf16* __restrict__ Bpk,
    const __bf16* __restrict__ xproj,
    float* __restrict__ st_f32) {
    __shared__ __align__(16) char smem[8704];
    int(*ell_lds)[68] = (int(*)[68])smem;                    // [16][68] int: 4352 B
    __bf16(*aggr_lds)[136] = (__bf16(*)[136])(smem + 4352);  // [16][136]: 4352 B
    float(*tile)[132] = (float(*)[132])smem;                 // [16][132] f32: 8448 B

    int tid = threadIdx.x;
    int wv = tid >> 6, lane = tid & 63;
    int q = lane >> 4, f = lane & 15;
    int nb = blockIdx.x * NPB;

    int pn_l = perm[nb + (lane & 15)];    // this lane's node (lane&15 slot)
    int degv = deg[pn_l]; if (degv > MAXW) degv = MAXW;
    // block max degree (sorted -> nearly uniform) via 16-lane butterfly
    int bmx = degv;
#pragma unroll
    for (int m = 1; m <= 8; m <<= 1) {
        int o = __shfl_xor(bmx, m);
        bmx = o > bmx ? o : bmx;
    }
    int nslots = (bmx + 7) & ~7;

    // stage ELL: 256 threads = 16 rows x 16 int4-groups, one shot, masked
    {
        int n = tid & 15, g = tid >> 4;
        if (g * 4 < nslots)
            *(int4*)&ell_lds[n][g * 4] = *(const int4*)&ell[(size_t)pn_l * MAXW + g * 4];
    }
    __syncthreads();

    // ---- phase 1: quarter q of wave wv gathers node n = wv*4+q ----
    int n = wv * 4 + q;
    int cn = __shfl(degv, n);
    int steps = (cn + 7) >> 3;
    float acc[8];
#pragma unroll
    for (int j = 0; j < 8; ++j) acc[j] = 0.f;
    for (int s = 0; s < steps; ++s) {
        int b0 = s * 8;
        int idx[8];
#pragma unroll
        for (int u = 0; u < 8; ++u) idx[u] = ell_lds[n][b0 + u];
        bf16x8 v[8];
#pragma unroll
        for (int u = 0; u < 8; ++u)
            v[u] = *(const bf16x8*)(state_in + (size_t)idx[u] * HID + f * 8);
#pragma unroll
        for (int j = 0; j < 8; ++j) {
            float a0 = 0.f;
#pragma unroll
            for (int u = 0; u < 8; ++u) a0 += (float)v[u][j];
            acc[j] += a0;
        }
    }
    {
        bf16x8 o;
#pragma unroll
        for (int j = 0; j < 8; ++j) o[j] = (__bf16)acc[j];
        *(bf16x8*)&aggr_lds[n][f * 8] = o;
    }
    __syncthreads();

    // ---- phase 2: M=16 GEMM; wave wv owns output cols wv*32 .. +31 ----
    bf16x8 a[4];
#pragma unroll
    for (int c = 0; c < 4; ++c)
        a[c] = *(const bf16x8*)&aggr_lds[f][c * 32 + q * 8];
    __syncthreads();   // overlay safety: aggr/ell reads done before tile writes

#pragma unroll
    for (int tl = 0; tl < 2; ++tl) {
        int t = wv * 2 + tl;
        floatx4 acc_t = {0.f, 0.f, 0.f, 0.f};
#pragma unroll
        for (int c = 0; c < 4; ++c) {
            bf16x8 b = *(const bf16x8*)(Bpk + (((c * 8 + t) * 64 + lane) << 3));
            acc_t = __builtin_amdgcn_mfma_f32_16x16x32_bf16(a[c], b, acc_t, 0, 0, 0);
        }
#pragma unroll
        for (int r = 0; r < 4; ++r)
            tile[q * 4 + r][t * 16 + f] = acc_t[r];
    }

    // epilogue (wave-private cols): rows 0..15, cols wv*32 + (lane&3)*8 .. +7
    int row = lane >> 2, seg = lane & 3;
    int pn_row = __shfl(pn_l, row);
    size_t goff = (size_t)pn_row * HID + wv * 32 + seg * 8;
    int lcol = wv * 32 + seg * 8;
    float v[8];
    bf16x8 bx = *(const bf16x8*)(xproj + goff);
#pragma unroll
    for (int j = 0; j < 2; ++j) {
        floatx4 t4 = *(floatx4*)&tile[row][lcol + j * 4];
        v[j * 4] = t4[0]; v[j * 4 + 1] = t4[1]; v[j * 4 + 2] = t4[2]; v[j * 4 + 3] = t4[3];
    }
#pragma unroll
    for (int k = 0; k < 8; ++k) v[k] = tanhf(v[k] + (float)bx[k]);
    {
        bf16x8 o;
#pragma unroll
        for (int k = 0; k < 8; ++k) o[k] = (__bf16)v[k];
        *(bf16x8*)(state_out + goff) = o;
    }
    if (st_f32) {
#pragma unroll
        for (int j = 0; j < 2; ++j) {
            float4 o = {v[j * 4], v[j * 4 + 1], v[j * 4 + 2], v[j * 4 + 3]};
            *(float4*)(st_f32 + goff + j * 4) = o;
        }
    }
}

extern "C" void kernel_launch(void* const* d_in, const int* in_sizes, int n_in,
                              void* d_out, int out_size, void* d_ws, size_t ws_size,
                              hipStream_t stream) {
    const int* ei = (const int*)d_in[0];       // edge_index [2][E]
    const float* x = (const float*)d_in[1];    // [N][128] f32
    const float* w_in0 = (const float*)d_in[2];
    const float* w_rec0 = (const float*)d_in[3];
    const float* w_in1 = (const float*)d_in[4];
    const float* w_rec1 = (const float*)d_in[5];
    float* out = (float*)d_out;

    // workspace carve (~42 MB total)
    __bf16* xproj_bf = (__bf16*)d_ws;              // NH bf16 (10.24 MB)
    __bf16* stateA = xproj_bf + NH;                // NH + HID bf16 (pad row)
    __bf16* stateB = stateA + NH + HID;            // NH + HID bf16 (pad row); x_bf first
    __bf16* packs = stateB + NH + HID;             // 4 x 16384 bf16
    int* deg = (int*)(packs + 4 * 16384);          // N
    int* hist = deg + N_NODES;                     // 80 (65 used)
    int* cursor = hist + 80;                       // 80 (65 used)
    int* perm = cursor + 80;                       // N
    int* ell = perm + N_NODES;                     // N*MAXW (10.24 MB)
    __bf16* pk_in0 = packs;
    __bf16* pk_rec0 = packs + 16384;
    __bf16* pk_in1 = packs + 2 * 16384;
    __bf16* pk_rec1 = packs + 3 * 16384;

    init_kernel<<<N_EDGES / 256, 256, 0, stream>>>(ell, deg, hist, stateA + NH,
                                                   stateB + NH);
    build_ell_kernel<<<N_EDGES / 256, 256, 0, stream>>>(ei, deg, ell);
    hist_kernel<<<(N_NODES + 255) / 256, 256, 0, stream>>>(deg, hist);
    scan_kernel<<<1, 64, 0, stream>>>(hist, cursor);
    build_perm_kernel<<<(N_NODES + 255) / 256, 256, 0, stream>>>(deg, cursor, perm);
    pack_w_kernel<<<64, 256, 0, stream>>>(w_in0, pk_in0, 1);   // B = w_in0^T
    pack_w_kernel<<<64, 256, 0, stream>>>(w_rec0, pk_rec0, 0); // B = w_rec0
    pack_w_kernel<<<64, 256, 0, stream>>>(w_in1, pk_in1, 1);
    pack_w_kernel<<<64, 256, 0, stream>>>(w_rec1, pk_rec1, 0);
    cast_bf16_kernel<<<NH / 4 / 256, 256, 0, stream>>>(x, stateB);  // x_bf in stateB

    for (int layer = 0; layer < 2; ++layer) {
        const __bf16* pk_in = layer ? pk_in1 : pk_in0;
        const __bf16* pk_rec = layer ? pk_rec1 : pk_rec0;
        // xproj = (layer ? h0 : x_bf) @ w_in^T ; stateA = tanh(xproj).
        // layer 1: A aliases st_bf (each wave reads its own rows first — safe).
        const __bf16* xin = layer ? stateA : stateB;
        mfma_gemm_kernel<<<625, 256, 0, stream>>>(xin, pk_in, xproj_bf, stateA);
        // 8 ping-pong iterations: A->B, B->A, ... ends in stateA.
        for (int it = 0; it < ITERS; ++it) {
            const __bf16* sin = (it & 1) ? stateB : stateA;
            __bf16* sout = (it & 1) ? stateA : stateB;
            float* f32out = (layer == 1 && it == ITERS - 1) ? out : nullptr;
            fused_iter_kernel<<<FBLK, 256, 0, stream>>>(sin, sout, ell, deg, perm,
                                                        pk_rec, xproj_bf, f32out);
        }
    }
}

// Round 8
// 550.244 us; speedup vs baseline: 1.3455x; 1.3017x over previous
//
#include <hip/hip_runtime.h>
#include <math.h>

#define N_NODES 40000
#define N_EDGES 640000
#define HID 128
#define MAXW 64      // in-degree ~ Poisson(16); P(deg > 64) ~ 1e-19 -> never drops edges
#define ITERS 8      // full iterations after initial state = tanh(xproj)
#define NH (N_NODES * HID)
#define NPB 16                  // nodes per fused block
#define FBLK (N_NODES / NPB)    // 2500 fused blocks

typedef __bf16 bf16x8 __attribute__((ext_vector_type(8)));
typedef __bf16 bf16x4 __attribute__((ext_vector_type(4)));
typedef float floatx4 __attribute__((ext_vector_type(4)));

// Fill ELL with pad index N_NODES, zero deg, zero pad rows of both state buffers.
__global__ __launch_bounds__(256) void init_kernel(int* __restrict__ ell,
                                                   int* __restrict__ deg,
                                                   __bf16* __restrict__ padA,
                                                   __bf16* __restrict__ padB) {
    int i = blockIdx.x * 256 + threadIdx.x;   // N_EDGES threads
    int4 pad = {N_NODES, N_NODES, N_NODES, N_NODES};
    ((int4*)ell)[i] = pad;                    // N*MAXW/4 = 640000 int4 exactly
    if (i < N_NODES) deg[i] = 0;
    if (i < HID / 8) {
        bf16x8 z;
#pragma unroll
        for (int j = 0; j < 8; ++j) z[j] = (__bf16)0.f;
        ((bf16x8*)padA)[i] = z;
        ((bf16x8*)padB)[i] = z;
    }
}

// Per-node atomics only (40000 addrs). Round 6/7 lesson: never atomic onto
// few addresses (bmax: 1250 addrs = 142us; hist: 65 addrs = 105us).
__global__ __launch_bounds__(256) void build_ell_kernel(const int* __restrict__ ei,
                                                        int* __restrict__ deg,
                                                        int* __restrict__ ell) {
    int e = blockIdx.x * 256 + threadIdx.x;
    if (e >= N_EDGES) return;
    int s = ei[e];            // src
    int d = ei[N_EDGES + e];  // dst
    int c = atomicAdd(&deg[d], 1);
    if (c < MAXW) ell[d * MAXW + c] = s;
}

// Pack W (or W^T) into B-fragment order for mfma_f32_16x16x32_bf16:
// pk[((c*8+t)*64 + lane)*8 + j] = B[k = c*32 + (lane>>4)*8 + j][n = t*16 + (lane&15)]
__global__ __launch_bounds__(256) void pack_w_kernel(const float* __restrict__ w,
                                                     __bf16* __restrict__ pk, int trans) {
    int f = blockIdx.x * 256 + threadIdx.x;  // 16384 total
    int j = f & 7, l = (f >> 3) & 63, t = (f >> 9) & 7, c = f >> 12;
    int k = c * 32 + (l >> 4) * 8 + j;
    int n = t * 16 + (l & 15);
    float v = trans ? w[n * HID + k] : w[k * HID + n];
    pk[f] = (__bf16)v;
}

__global__ __launch_bounds__(256) void cast_bf16_kernel(const float* __restrict__ x,
                                                        __bf16* __restrict__ o) {
    int i = blockIdx.x * 256 + threadIdx.x;   // NH/4 threads
    float4 v = ((const float4*)x)[i];
    bf16x4 b;
    b[0] = (__bf16)v.x; b[1] = (__bf16)v.y; b[2] = (__bf16)v.z; b[3] = (__bf16)v.w;
    ((bf16x4*)o)[i] = b;
}

// xproj GEMM (runs twice): xp_bf = A @ B (bf16 pre-tanh), st_bf = tanh(...).
__global__ __launch_bounds__(256) void mfma_gemm_kernel(const __bf16* A,
                                                        const __bf16* __restrict__ Bpk,
                                                        __bf16* __restrict__ xp_bf,
                                                        __bf16* st_bf) {
    __shared__ float tile[4][16][132];
    int tid = threadIdx.x;
    int wv = tid >> 6, lane = tid & 63;
    int q = lane >> 4, cl = lane & 15;

    int row_a = blockIdx.x * 64 + wv * 16 + cl;
    bf16x8 a[4];
#pragma unroll
    for (int c = 0; c < 4; ++c)
        a[c] = *(const bf16x8*)(A + (size_t)row_a * HID + c * 32 + q * 8);

#pragma unroll
    for (int t = 0; t < 8; ++t) {
        floatx4 acc_t = {0.f, 0.f, 0.f, 0.f};
#pragma unroll
        for (int c = 0; c < 4; ++c) {
            bf16x8 b = *(const bf16x8*)(Bpk + (((c * 8 + t) * 64 + lane) << 3));
            acc_t = __builtin_amdgcn_mfma_f32_16x16x32_bf16(a[c], b, acc_t, 0, 0, 0);
        }
#pragma unroll
        for (int r = 0; r < 4; ++r)
            tile[wv][q * 4 + r][t * 16 + cl] = acc_t[r];
    }
    int row = lane >> 2, seg = lane & 3;
    size_t goff = (size_t)(blockIdx.x * 64 + wv * 16 + row) * HID + seg * 32;
    float v[32];
#pragma unroll
    for (int j = 0; j < 8; ++j) {
        floatx4 t4 = *(floatx4*)&tile[wv][row][seg * 32 + j * 4];
        v[j * 4] = t4[0]; v[j * 4 + 1] = t4[1]; v[j * 4 + 2] = t4[2]; v[j * 4 + 3] = t4[3];
    }
#pragma unroll
    for (int j = 0; j < 4; ++j) {
        bf16x8 o;
#pragma unroll
        for (int k = 0; k < 8; ++k) o[k] = (__bf16)v[j * 8 + k];
        *(bf16x8*)(xp_bf + goff + j * 8) = o;   // pre-tanh, bf16
    }
#pragma unroll
    for (int i = 0; i < 32; ++i) v[i] = tanhf(v[i]);
#pragma unroll
    for (int j = 0; j < 4; ++j) {
        bf16x8 o;
#pragma unroll
        for (int k = 0; k < 8; ++k) o[k] = (__bf16)v[j * 8 + k];
        *(bf16x8*)(st_bf + goff + j * 8) = o;
    }
}

// Fused iteration v5: state_out = tanh(xproj + gather(state_in) @ W).
// 16 nodes/block, 2500 blocks, 8.7 KB LDS, <=64 VGPR -> 32 waves/CU.
// Gather: one node per 16-lane quarter, exact per-node trip counts in
// 4-load batches (padding waste ~1.5 slots/node vs 3.7 with 8-batches);
// ELL staged only to block-max degree (in-wave butterfly, no atomics).
// Pad slots hit the zero row at state_in + N_NODES*HID.
__global__ __launch_bounds__(256, 8) void fused_iter_kernel(
    const __bf16* __restrict__ state_in,
    __bf16* __restrict__ state_out,
    const int* __restrict__ ell,
    const int* __restrict__ deg,
    const __bf16* __restrict__ Bpk,
    const __bf16* __restrict__ xproj,
    float* __restrict__ st_f32) {
    __shared__ __align__(16) char smem[8704];
    int(*ell_lds)[68] = (int(*)[68])smem;                    // [16][68] int: 4352 B
    __bf16(*aggr_lds)[136] = (__bf16(*)[136])(smem + 4352);  // [16][136]: 4352 B
    float(*tile)[132] = (float(*)[132])smem;                 // [16][132] f32: 8448 B

    int tid = threadIdx.x;
    int wv = tid >> 6, lane = tid & 63;
    int q = lane >> 4, f = lane & 15;
    int nb = blockIdx.x * NPB;

    int degv = deg[nb + (lane & 15)];
    if (degv > MAXW) degv = MAXW;
    // block max degree via 16-lane butterfly (no atomics)
    int bmx = degv;
#pragma unroll
    for (int m = 1; m <= 8; m <<= 1) {
        int o = __shfl_xor(bmx, m);
        bmx = o > bmx ? o : bmx;
    }
    int nslots = (bmx + 3) & ~3;

    // stage ELL: 256 threads = 16 rows x 16 int4-groups, one shot, masked
    {
        int n = tid & 15, g = tid >> 4;
        if (g * 4 < nslots)
            *(int4*)&ell_lds[n][g * 4] = *(const int4*)&ell[(size_t)(nb + n) * MAXW + g * 4];
    }
    __syncthreads();

    // ---- phase 1: quarter q of wave wv gathers node n = wv*4+q ----
    int n = wv * 4 + q;
    int cn = __shfl(degv, n);          // lane n holds deg[nb+n]
    int steps = (cn + 3) >> 2;         // exact 4-granular trip count
    float acc[8];
#pragma unroll
    for (int j = 0; j < 8; ++j) acc[j] = 0.f;
    for (int s = 0; s < steps; ++s) {
        int b0 = s * 4;
        int idx[4];
#pragma unroll
        for (int u = 0; u < 4; ++u) idx[u] = ell_lds[n][b0 + u];
        bf16x8 v[4];
#pragma unroll
        for (int u = 0; u < 4; ++u)
            v[u] = *(const bf16x8*)(state_in + (size_t)idx[u] * HID + f * 8);
#pragma unroll
        for (int j = 0; j < 8; ++j)
            acc[j] += ((float)v[0][j] + (float)v[1][j]) + ((float)v[2][j] + (float)v[3][j]);
    }
    {
        bf16x8 o;
#pragma unroll
        for (int j = 0; j < 8; ++j) o[j] = (__bf16)acc[j];
        *(bf16x8*)&aggr_lds[n][f * 8] = o;
    }
    __syncthreads();

    // ---- phase 2: M=16 GEMM; wave wv owns output cols wv*32 .. +31 ----
    bf16x8 a[4];
#pragma unroll
    for (int c = 0; c < 4; ++c)
        a[c] = *(const bf16x8*)&aggr_lds[f][c * 32 + q * 8];
    __syncthreads();   // overlay safety: aggr/ell reads done before tile writes

#pragma unroll
    for (int tl = 0; tl < 2; ++tl) {
        int t = wv * 2 + tl;
        floatx4 acc_t = {0.f, 0.f, 0.f, 0.f};
#pragma unroll
        for (int c = 0; c < 4; ++c) {
            bf16x8 b = *(const bf16x8*)(Bpk + (((c * 8 + t) * 64 + lane) << 3));
            acc_t = __builtin_amdgcn_mfma_f32_16x16x32_bf16(a[c], b, acc_t, 0, 0, 0);
        }
#pragma unroll
        for (int r = 0; r < 4; ++r)
            tile[q * 4 + r][t * 16 + f] = acc_t[r];
    }

    // epilogue (wave-private cols): rows 0..15, cols wv*32 + (lane&3)*8 .. +7
    int row = lane >> 2, seg = lane & 3;
    size_t goff = (size_t)(nb + row) * HID + wv * 32 + seg * 8;
    int lcol = wv * 32 + seg * 8;
    float v[8];
    bf16x8 bx = *(const bf16x8*)(xproj + goff);
#pragma unroll
    for (int j = 0; j < 2; ++j) {
        floatx4 t4 = *(floatx4*)&tile[row][lcol + j * 4];
        v[j * 4] = t4[0]; v[j * 4 + 1] = t4[1]; v[j * 4 + 2] = t4[2]; v[j * 4 + 3] = t4[3];
    }
#pragma unroll
    for (int k = 0; k < 8; ++k) v[k] = tanhf(v[k] + (float)bx[k]);
    {
        bf16x8 o;
#pragma unroll
        for (int k = 0; k < 8; ++k) o[k] = (__bf16)v[k];
        *(bf16x8*)(state_out + goff) = o;
    }
    if (st_f32) {
#pragma unroll
        for (int j = 0; j < 2; ++j) {
            float4 o = {v[j * 4], v[j * 4 + 1], v[j * 4 + 2], v[j * 4 + 3]};
            *(float4*)(st_f32 + goff + j * 4) = o;
        }
    }
}

extern "C" void kernel_launch(void* const* d_in, const int* in_sizes, int n_in,
                              void* d_out, int out_size, void* d_ws, size_t ws_size,
                              hipStream_t stream) {
    const int* ei = (const int*)d_in[0];       // edge_index [2][E]
    const float* x = (const float*)d_in[1];    // [N][128] f32
    const float* w_in0 = (const float*)d_in[2];
    const float* w_rec0 = (const float*)d_in[3];
    const float* w_in1 = (const float*)d_in[4];
    const float* w_rec1 = (const float*)d_in[5];
    float* out = (float*)d_out;

    // workspace carve (~42 MB total)
    __bf16* xproj_bf = (__bf16*)d_ws;              // NH bf16 (10.24 MB)
    __bf16* stateA = xproj_bf + NH;                // NH + HID bf16 (pad row)
    __bf16* stateB = stateA + NH + HID;            // NH + HID bf16 (pad row); x_bf first
    __bf16* packs = stateB + NH + HID;             // 4 x 16384 bf16
    int* deg = (int*)(packs + 4 * 16384);          // N
    int* ell = deg + N_NODES;                      // N*MAXW (10.24 MB)
    __bf16* pk_in0 = packs;
    __bf16* pk_rec0 = packs + 16384;
    __bf16* pk_in1 = packs + 2 * 16384;
    __bf16* pk_rec1 = packs + 3 * 16384;

    init_kernel<<<N_EDGES / 256, 256, 0, stream>>>(ell, deg, stateA + NH, stateB + NH);
    build_ell_kernel<<<N_EDGES / 256, 256, 0, stream>>>(ei, deg, ell);
    pack_w_kernel<<<64, 256, 0, stream>>>(w_in0, pk_in0, 1);   // B = w_in0^T
    pack_w_kernel<<<64, 256, 0, stream>>>(w_rec0, pk_rec0, 0); // B = w_rec0
    pack_w_kernel<<<64, 256, 0, stream>>>(w_in1, pk_in1, 1);
    pack_w_kernel<<<64, 256, 0, stream>>>(w_rec1, pk_rec1, 0);
    cast_bf16_kernel<<<NH / 4 / 256, 256, 0, stream>>>(x, stateB);  // x_bf in stateB

    for (int layer = 0; layer < 2; ++layer) {
        const __bf16* pk_in = layer ? pk_in1 : pk_in0;
        const __bf16* pk_rec = layer ? pk_rec1 : pk_rec0;
        // xproj = (layer ? h0 : x_bf) @ w_in^T ; stateA = tanh(xproj).
        // layer 1: A aliases st_bf (each wave reads its own rows first — safe).
        const __bf16* xin = layer ? stateA : stateB;
        mfma_gemm_kernel<<<625, 256, 0, stream>>>(xin, pk_in, xproj_bf, stateA);
        // 8 ping-pong iterations: A->B, B->A, ... ends in stateA.
        for (int it = 0; it < ITERS; ++it) {
            const __bf16* sin = (it & 1) ? stateB : stateA;
            __bf16* sout = (it & 1) ? stateA : stateB;
            float* f32out = (layer == 1 && it == ITERS - 1) ? out : nullptr;
            fused_iter_kernel<<<FBLK, 256, 0, stream>>>(sin, sout, ell, deg,
                                                        pk_rec, xproj_bf, f32out);
        }
    }
}

// Round 9
// 542.242 us; speedup vs baseline: 1.3654x; 1.0148x over previous
//
#include <hip/hip_runtime.h>
#include <math.h>

#define N_NODES 40000
#define N_EDGES 640000
#define HID 128
#define MAXW 64      // in-degree ~ Poisson(16); P(deg > 64) ~ 1e-19 -> never drops edges
#define ITERS 8      // full iterations after initial state = tanh(xproj)
#define NH (N_NODES * HID)
#define NPB 16                  // nodes per fused block
#define FBLK (N_NODES / NPB)    // 2500 fused blocks
#define DSTRIDE 32              // degree-counter pad: 1 counter per 128B line

typedef __bf16 bf16x8 __attribute__((ext_vector_type(8)));
typedef __bf16 bf16x4 __attribute__((ext_vector_type(4)));
typedef float floatx4 __attribute__((ext_vector_type(4)));

// Fill ELL with pad index N_NODES, zero padded deg counters, zero state pad rows.
__global__ __launch_bounds__(256) void init_kernel(int* __restrict__ ell,
                                                   int* __restrict__ degp,
                                                   __bf16* __restrict__ padA,
                                                   __bf16* __restrict__ padB) {
    int i = blockIdx.x * 256 + threadIdx.x;   // N_EDGES threads
    int4 pad = {N_NODES, N_NODES, N_NODES, N_NODES};
    ((int4*)ell)[i] = pad;                    // N*MAXW/4 = 640000 int4 exactly
    if (i < N_NODES * DSTRIDE / 4) {
        int4 z = {0, 0, 0, 0};
        ((int4*)degp)[i] = z;                 // 320000 int4
    }
    if (i < HID / 8) {
        bf16x8 z;
#pragma unroll
        for (int j = 0; j < 8; ++j) z[j] = (__bf16)0.f;
        ((bf16x8*)padA)[i] = z;
        ((bf16x8*)padB)[i] = z;
    }
}

// Degree counters padded to one per 128B L2 line: round 8 showed 16 counters/line
// -> ~256 serialized atomics per line -> 52us. (Rounds 6/7 lesson, line-granular.)
__global__ __launch_bounds__(256) void build_ell_kernel(const int* __restrict__ ei,
                                                        int* __restrict__ degp,
                                                        int* __restrict__ ell) {
    int e = blockIdx.x * 256 + threadIdx.x;
    if (e >= N_EDGES) return;
    int s = ei[e];            // src
    int d = ei[N_EDGES + e];  // dst
    int c = atomicAdd(&degp[d * DSTRIDE], 1);
    if (c < MAXW) ell[d * MAXW + c] = s;
}

__global__ __launch_bounds__(256) void compact_deg_kernel(const int* __restrict__ degp,
                                                          int* __restrict__ deg) {
    int i = blockIdx.x * 256 + threadIdx.x;
    if (i >= N_NODES) return;
    int d = degp[i * DSTRIDE];
    deg[i] = d > MAXW ? MAXW : d;
}

// Pack W (or W^T) into B-fragment order for mfma_f32_16x16x32_bf16:
// pk[((c*8+t)*64 + lane)*8 + j] = B[k = c*32 + (lane>>4)*8 + j][n = t*16 + (lane&15)]
__global__ __launch_bounds__(256) void pack_w_kernel(const float* __restrict__ w,
                                                     __bf16* __restrict__ pk, int trans) {
    int f = blockIdx.x * 256 + threadIdx.x;  // 16384 total
    int j = f & 7, l = (f >> 3) & 63, t = (f >> 9) & 7, c = f >> 12;
    int k = c * 32 + (l >> 4) * 8 + j;
    int n = t * 16 + (l & 15);
    float v = trans ? w[n * HID + k] : w[k * HID + n];
    pk[f] = (__bf16)v;
}

__global__ __launch_bounds__(256) void cast_bf16_kernel(const float* __restrict__ x,
                                                        __bf16* __restrict__ o) {
    int i = blockIdx.x * 256 + threadIdx.x;   // NH/4 threads
    float4 v = ((const float4*)x)[i];
    bf16x4 b;
    b[0] = (__bf16)v.x; b[1] = (__bf16)v.y; b[2] = (__bf16)v.z; b[3] = (__bf16)v.w;
    ((bf16x4*)o)[i] = b;
}

// xproj GEMM (runs twice): xp_bf = A @ B (bf16 pre-tanh), st_bf = tanh(...).
__global__ __launch_bounds__(256) void mfma_gemm_kernel(const __bf16* A,
                                                        const __bf16* __restrict__ Bpk,
                                                        __bf16* __restrict__ xp_bf,
                                                        __bf16* st_bf) {
    __shared__ float tile[4][16][132];
    int tid = threadIdx.x;
    int wv = tid >> 6, lane = tid & 63;
    int q = lane >> 4, cl = lane & 15;

    int row_a = blockIdx.x * 64 + wv * 16 + cl;
    bf16x8 a[4];
#pragma unroll
    for (int c = 0; c < 4; ++c)
        a[c] = *(const bf16x8*)(A + (size_t)row_a * HID + c * 32 + q * 8);

#pragma unroll
    for (int t = 0; t < 8; ++t) {
        floatx4 acc_t = {0.f, 0.f, 0.f, 0.f};
#pragma unroll
        for (int c = 0; c < 4; ++c) {
            bf16x8 b = *(const bf16x8*)(Bpk + (((c * 8 + t) * 64 + lane) << 3));
            acc_t = __builtin_amdgcn_mfma_f32_16x16x32_bf16(a[c], b, acc_t, 0, 0, 0);
        }
#pragma unroll
        for (int r = 0; r < 4; ++r)
            tile[wv][q * 4 + r][t * 16 + cl] = acc_t[r];
    }
    int row = lane >> 2, seg = lane & 3;
    size_t goff = (size_t)(blockIdx.x * 64 + wv * 16 + row) * HID + seg * 32;
    float v[32];
#pragma unroll
    for (int j = 0; j < 8; ++j) {
        floatx4 t4 = *(floatx4*)&tile[wv][row][seg * 32 + j * 4];
        v[j * 4] = t4[0]; v[j * 4 + 1] = t4[1]; v[j * 4 + 2] = t4[2]; v[j * 4 + 3] = t4[3];
    }
#pragma unroll
    for (int j = 0; j < 4; ++j) {
        bf16x8 o;
#pragma unroll
        for (int k = 0; k < 8; ++k) o[k] = (__bf16)v[j * 8 + k];
        *(bf16x8*)(xp_bf + goff + j * 8) = o;   // pre-tanh, bf16
    }
#pragma unroll
    for (int i = 0; i < 32; ++i) v[i] = tanhf(v[i]);
#pragma unroll
    for (int j = 0; j < 4; ++j) {
        bf16x8 o;
#pragma unroll
        for (int k = 0; k < 8; ++k) o[k] = (__bf16)v[j * 8 + k];
        *(bf16x8*)(st_bf + goff + j * 8) = o;
    }
}

// Fused iteration: state_out = tanh(xproj + gather(state_in) @ W).
// 16 nodes/block, 2500 blocks, 8.7 KB LDS, <=64 VGPR -> 32 waves/CU.
// Gather: one node per 16-lane quarter, exact 4-granular trip counts;
// ELL staged to block-max degree (in-wave butterfly, no atomics).
// Pad slots hit the zero row at state_in + N_NODES*HID.
// At ~28.5us/iter this moves ~187MB logical through L2/L3 at ~6.5 TB/s
// effective — the fabric ceiling for the pull-gather structure.
__global__ __launch_bounds__(256, 8) void fused_iter_kernel(
    const __bf16* __restrict__ state_in,
    __bf16* __restrict__ state_out,
    const int* __restrict__ ell,
    const int* __restrict__ deg,
    const __bf16* __restrict__ Bpk,
    const __bf16* __restrict__ xproj,
    float* __restrict__ st_f32) {
    __shared__ __align__(16) char smem[8704];
    int(*ell_lds)[68] = (int(*)[68])smem;                    // [16][68] int: 4352 B
    __bf16(*aggr_lds)[136] = (__bf16(*)[136])(smem + 4352);  // [16][136]: 4352 B
    float(*tile)[132] = (float(*)[132])smem;                 // [16][132] f32: 8448 B

    int tid = threadIdx.x;
    int wv = tid >> 6, lane = tid & 63;
    int q = lane >> 4, f = lane & 15;
    int nb = blockIdx.x * NPB;

    int degv = deg[nb + (lane & 15)];   // already clamped to MAXW
    // block max degree via 16-lane butterfly (no atomics)
    int bmx = degv;
#pragma unroll
    for (int m = 1; m <= 8; m <<= 1) {
        int o = __shfl_xor(bmx, m);
        bmx = o > bmx ? o : bmx;
    }
    int nslots = (bmx + 3) & ~3;

    // stage ELL: 256 threads = 16 rows x 16 int4-groups, one shot, masked
    {
        int n = tid & 15, g = tid >> 4;
        if (g * 4 < nslots)
            *(int4*)&ell_lds[n][g * 4] = *(const int4*)&ell[(size_t)(nb + n) * MAXW + g * 4];
    }
    __syncthreads();

    // ---- phase 1: quarter q of wave wv gathers node n = wv*4+q ----
    int n = wv * 4 + q;
    int cn = __shfl(degv, n);          // lane n holds deg[nb+n]
    int steps = (cn + 3) >> 2;         // exact 4-granular trip count
    float acc[8];
#pragma unroll
    for (int j = 0; j < 8; ++j) acc[j] = 0.f;
    for (int s = 0; s < steps; ++s) {
        int b0 = s * 4;
        int idx[4];
#pragma unroll
        for (int u = 0; u < 4; ++u) idx[u] = ell_lds[n][b0 + u];
        bf16x8 v[4];
#pragma unroll
        for (int u = 0; u < 4; ++u)
            v[u] = *(const bf16x8*)(state_in + (size_t)idx[u] * HID + f * 8);
#pragma unroll
        for (int j = 0; j < 8; ++j)
            acc[j] += ((float)v[0][j] + (float)v[1][j]) + ((float)v[2][j] + (float)v[3][j]);
    }
    {
        bf16x8 o;
#pragma unroll
        for (int j = 0; j < 8; ++j) o[j] = (__bf16)acc[j];
        *(bf16x8*)&aggr_lds[n][f * 8] = o;
    }
    __syncthreads();

    // ---- phase 2: M=16 GEMM; wave wv owns output cols wv*32 .. +31 ----
    bf16x8 a[4];
#pragma unroll
    for (int c = 0; c < 4; ++c)
        a[c] = *(const bf16x8*)&aggr_lds[f][c * 32 + q * 8];
    __syncthreads();   // overlay safety: aggr/ell reads done before tile writes

#pragma unroll
    for (int tl = 0; tl < 2; ++tl) {
        int t = wv * 2 + tl;
        floatx4 acc_t = {0.f, 0.f, 0.f, 0.f};
#pragma unroll
        for (int c = 0; c < 4; ++c) {
            bf16x8 b = *(const bf16x8*)(Bpk + (((c * 8 + t) * 64 + lane) << 3));
            acc_t = __builtin_amdgcn_mfma_f32_16x16x32_bf16(a[c], b, acc_t, 0, 0, 0);
        }
#pragma unroll
        for (int r = 0; r < 4; ++r)
            tile[q * 4 + r][t * 16 + f] = acc_t[r];
    }

    // epilogue (wave-private cols): rows 0..15, cols wv*32 + (lane&3)*8 .. +7
    int row = lane >> 2, seg = lane & 3;
    size_t goff = (size_t)(nb + row) * HID + wv * 32 + seg * 8;
    int lcol = wv * 32 + seg * 8;
    float v[8];
    bf16x8 bx = *(const bf16x8*)(xproj + goff);
#pragma unroll
    for (int j = 0; j < 2; ++j) {
        floatx4 t4 = *(floatx4*)&tile[row][lcol + j * 4];
        v[j * 4] = t4[0]; v[j * 4 + 1] = t4[1]; v[j * 4 + 2] = t4[2]; v[j * 4 + 3] = t4[3];
    }
#pragma unroll
    for (int k = 0; k < 8; ++k) v[k] = tanhf(v[k] + (float)bx[k]);
    {
        bf16x8 o;
#pragma unroll
        for (int k = 0; k < 8; ++k) o[k] = (__bf16)v[k];
        *(bf16x8*)(state_out + goff) = o;
    }
    if (st_f32) {
#pragma unroll
        for (int j = 0; j < 2; ++j) {
            float4 o = {v[j * 4], v[j * 4 + 1], v[j * 4 + 2], v[j * 4 + 3]};
            *(float4*)(st_f32 + goff + j * 4) = o;
        }
    }
}

extern "C" void kernel_launch(void* const* d_in, const int* in_sizes, int n_in,
                              void* d_out, int out_size, void* d_ws, size_t ws_size,
                              hipStream_t stream) {
    const int* ei = (const int*)d_in[0];       // edge_index [2][E]
    const float* x = (const float*)d_in[1];    // [N][128] f32
    const float* w_in0 = (const float*)d_in[2];
    const float* w_rec0 = (const float*)d_in[3];
    const float* w_in1 = (const float*)d_in[4];
    const float* w_rec1 = (const float*)d_in[5];
    float* out = (float*)d_out;

    // workspace carve (~47 MB total)
    __bf16* xproj_bf = (__bf16*)d_ws;              // NH bf16 (10.24 MB)
    __bf16* stateA = xproj_bf + NH;                // NH + HID bf16 (pad row)
    __bf16* stateB = stateA + NH + HID;            // NH + HID bf16 (pad row); x_bf first
    __bf16* packs = stateB + NH + HID;             // 4 x 16384 bf16
    int* deg = (int*)(packs + 4 * 16384);          // N (compact)
    int* degp = deg + N_NODES;                     // N*DSTRIDE (5.12 MB, padded counters)
    int* ell = degp + N_NODES * DSTRIDE;           // N*MAXW (10.24 MB)
    __bf16* pk_in0 = packs;
    __bf16* pk_rec0 = packs + 16384;
    __bf16* pk_in1 = packs + 2 * 16384;
    __bf16* pk_rec1 = packs + 3 * 16384;

    init_kernel<<<N_EDGES / 256, 256, 0, stream>>>(ell, degp, stateA + NH, stateB + NH);
    build_ell_kernel<<<N_EDGES / 256, 256, 0, stream>>>(ei, degp, ell);
    compact_deg_kernel<<<(N_NODES + 255) / 256, 256, 0, stream>>>(degp, deg);
    pack_w_kernel<<<64, 256, 0, stream>>>(w_in0, pk_in0, 1);   // B = w_in0^T
    pack_w_kernel<<<64, 256, 0, stream>>>(w_rec0, pk_rec0, 0); // B = w_rec0
    pack_w_kernel<<<64, 256, 0, stream>>>(w_in1, pk_in1, 1);
    pack_w_kernel<<<64, 256, 0, stream>>>(w_rec1, pk_rec1, 0);
    cast_bf16_kernel<<<NH / 4 / 256, 256, 0, stream>>>(x, stateB);  // x_bf in stateB

    for (int layer = 0; layer < 2; ++layer) {
        const __bf16* pk_in = layer ? pk_in1 : pk_in0;
        const __bf16* pk_rec = layer ? pk_rec1 : pk_rec0;
        // xproj = (layer ? h0 : x_bf) @ w_in^T ; stateA = tanh(xproj).
        // layer 1: A aliases st_bf (each wave reads its own rows first — safe).
        const __bf16* xin = layer ? stateA : stateB;
        mfma_gemm_kernel<<<625, 256, 0, stream>>>(xin, pk_in, xproj_bf, stateA);
        // 8 ping-pong iterations: A->B, B->A, ... ends in stateA.
        for (int it = 0; it < ITERS; ++it) {
            const __bf16* sin = (it & 1) ? stateB : stateA;
            __bf16* sout = (it & 1) ? stateA : stateB;
            float* f32out = (layer == 1 && it == ITERS - 1) ? out : nullptr;
            fused_iter_kernel<<<FBLK, 256, 0, stream>>>(sin, sout, ell, deg,
                                                        pk_rec, xproj_bf, f32out);
        }
    }
}